// Round 14
// baseline (205.802 us; speedup 1.0000x reference)
//
#include <hip/hip_runtime.h>
#include <math.h>

static constexpr int NN    = 100000;
static constexpr int NBUCK = (NN + 255) / 256;   // 391 buckets of 256 nodes
static constexpr int NBLK_A = 256;               // edge-pass blocks

#define CDIV(a,b) (((a)+(b)-1)/(b))

typedef __attribute__((ext_vector_type(8))) short bf16x8;
typedef __attribute__((ext_vector_type(4))) float f32x4;

// bf16 helpers (round-to-nearest-even store, shift load)
__device__ __forceinline__ float bf2f(unsigned short u) {
    return __uint_as_float(((unsigned)u) << 16);
}
__device__ __forceinline__ unsigned short f2bf(float f) {
    unsigned u = __float_as_uint(f);
    u += 0x7fffu + ((u >> 16) & 1u);
    return (unsigned short)(u >> 16);
}

// ------------------------------------------------------------------
// A1: blocks 0..255: per-block bucket counts -> gcnt[bucket][block].
// Blocks 256,257: convert W1 to swizzled bf16 image.
__global__ __launch_bounds__(256) void k_count(const int* __restrict__ dst,
                                               const float* __restrict__ W1,
                                               int* __restrict__ gcnt,
                                               unsigned short* __restrict__ WT,
                                               int E, int chunk) {
    const int b = blockIdx.x;
    const int t = threadIdx.x;
    if (b >= NBLK_A) {
        int base = (b - NBLK_A) * 8192 + t;   // 2 blocks x 8192
        #pragma unroll
        for (int i = 0; i < 32; i++) {
            int idx = base + i * 256;
            int k = idx >> 5, c = idx & 31;
            WT[c * 512 + (((k >> 3) ^ (c & 7)) << 3) + (k & 7)] = f2bf(W1[idx]);
        }
        return;
    }
    __shared__ int lc[NBUCK];
    for (int i = t; i < NBUCK; i += 256) lc[i] = 0;
    __syncthreads();
    int e0 = b * chunk;
    int e1 = e0 + chunk; if (e1 > E) e1 = E;
    for (int e = e0 + t; e < e1; e += 256)
        atomicAdd(&lc[dst[e] >> 8], 1);
    __syncthreads();
    for (int i = t; i < NBUCK; i += 256)
        gcnt[i * NBLK_A + b] = lc[i];
}

// A2: per-bucket exclusive scan over the 256 block-counts -> gofs, totals
__global__ __launch_bounds__(256) void k_scan2(const int* __restrict__ gcnt,
                                               int* __restrict__ gofs,
                                               int* __restrict__ bcnt) {
    const int b = blockIdx.x, t = threadIdx.x;
    __shared__ int sm[256];
    int v = gcnt[b * NBLK_A + t];
    sm[t] = v; __syncthreads();
    for (int off = 1; off < 256; off <<= 1) {
        int u = (t >= off) ? sm[t - off] : 0;
        __syncthreads();
        sm[t] += u;
        __syncthreads();
    }
    gofs[b * NBLK_A + t] = sm[t] - v;
    if (t == 255) bcnt[b] = sm[255];
}

// A3: exclusive scan of bucket totals -> bbase
__global__ __launch_bounds__(512) void k_scanB(const int* __restrict__ bcnt,
                                               int* __restrict__ bbase, int E) {
    __shared__ int sm[512];
    int t = threadIdx.x;
    int v = (t < NBUCK) ? bcnt[t] : 0;
    sm[t] = v; __syncthreads();
    for (int off = 1; off < 512; off <<= 1) {
        int u = (t >= off) ? sm[t - off] : 0;
        __syncthreads();
        sm[t] += u;
        __syncthreads();
    }
    if (t < NBUCK) bbase[t] = sm[t] - v;
    if (t == 0) bbase[NBUCK] = E;
}

// A4: single-pass partition: run starts known per (bucket, block)
__global__ __launch_bounds__(256) void k_bpart(const int* __restrict__ src,
                                               const int* __restrict__ dst,
                                               const int* __restrict__ bbase,
                                               const int* __restrict__ gofs,
                                               unsigned int* __restrict__ part,
                                               int E, int chunk) {
    __shared__ int boff[NBUCK];
    __shared__ int lc[NBUCK];
    const int blk = blockIdx.x;
    for (int i = threadIdx.x; i < NBUCK; i += 256) {
        boff[i] = bbase[i] + gofs[i * NBLK_A + blk];
        lc[i] = 0;
    }
    __syncthreads();
    int e0 = blk * chunk;
    int e1 = e0 + chunk; if (e1 > E) e1 = E;
    for (int e = e0 + threadIdx.x; e < e1; e += 256) {
        int d = dst[e];
        int b = d >> 8;
        int pos = boff[b] + atomicAdd(&lc[b], 1);
        part[pos] = ((unsigned)src[e] << 8) | (unsigned)(d & 255);
    }
}

// B: per-bucket CSR finalize: row_ptr, dinv, col (all writes bucket-local)
__global__ __launch_bounds__(256) void k_bbuild(const unsigned int* __restrict__ part,
                                                const int* __restrict__ bbase,
                                                int* __restrict__ row_ptr,
                                                float* __restrict__ dinv,
                                                int* __restrict__ col, int n, int E) {
    __shared__ int hist[256];
    __shared__ int excl[256];
    __shared__ int fill[256];
    const int b = blockIdx.x;
    const int t = threadIdx.x;
    const int e0 = bbase[b], e1 = bbase[b + 1];
    hist[t] = 0; fill[t] = 0;
    __syncthreads();
    for (int e = e0 + t; e < e1; e += 256)
        atomicAdd(&hist[part[e] & 255], 1);
    __syncthreads();
    int v = hist[t];
    excl[t] = v; __syncthreads();
    for (int off = 1; off < 256; off <<= 1) {
        int u = (t >= off) ? excl[t - off] : 0;
        __syncthreads();
        excl[t] += u;
        __syncthreads();
    }
    int ex = excl[t] - v;
    int g = b * 256 + t;
    if (g < n) {
        row_ptr[g] = e0 + ex;
        dinv[g] = rsqrtf((float)(v + 1));
    }
    if (b == 0 && t == 0) row_ptr[n] = E;
    excl[t] = e0 + ex;
    __syncthreads();
    for (int e = e0 + t; e < e1; e += 256) {
        unsigned u = part[e];
        int ld = u & 255;
        int pos = excl[ld] + atomicAdd(&fill[ld], 1);
        col[pos] = (int)(u >> 8);
    }
}

// ------------------------------------------------------------------
// Layer-1 GEMM via MFMA bf16 (proven R10 structure).
__global__ __launch_bounds__(256) void k_gemm1(const float* __restrict__ X,
                                               const unsigned short* __restrict__ WT,
                                               const float* __restrict__ dinv,
                                               unsigned short* __restrict__ OUT,
                                               int nrows) {
    __shared__ unsigned short wt[32][512];   // 32 KB
    const int t = threadIdx.x;
    {
        const uint4* s = (const uint4*)WT;
        uint4* d = (uint4*)&wt[0][0];
        #pragma unroll
        for (int i = 0; i < 8; i++) d[t + 256 * i] = s[t + 256 * i];
    }
    __syncthreads();

    const int lane  = t & 63;
    const int w     = t >> 6;
    const int grow0 = blockIdx.x * 64 + w * 16;
    const int m     = lane & 15;
    const int kb    = lane >> 4;             // 0..3
    int row = grow0 + m; if (row > nrows - 1) row = nrows - 1;
    const float* xrow = X + (size_t)row * 512 + kb * 8;

    f32x4 acc0 = {0.f, 0.f, 0.f, 0.f};
    f32x4 acc1 = {0.f, 0.f, 0.f, 0.f};
    const int mx  = m & 7;
    const unsigned short* wrow0 = &wt[m][0];
    const unsigned short* wrow1 = &wt[m + 16][0];

    #pragma unroll 4
    for (int kk = 0; kk < 512; kk += 32) {
        float4 xa = *(const float4*)(xrow + kk);
        float4 xb = *(const float4*)(xrow + kk + 4);
        bf16x8 a;
        a[0] = (short)f2bf(xa.x); a[1] = (short)f2bf(xa.y);
        a[2] = (short)f2bf(xa.z); a[3] = (short)f2bf(xa.w);
        a[4] = (short)f2bf(xb.x); a[5] = (short)f2bf(xb.y);
        a[6] = (short)f2bf(xb.z); a[7] = (short)f2bf(xb.w);
        const int g = (kk >> 3) + kb;        // 0..63
        bf16x8 b0 = *(const bf16x8*)&wrow0[((g ^ mx) & 63) * 8];
        bf16x8 b1 = *(const bf16x8*)&wrow1[((g ^ mx) & 63) * 8];
        acc0 = __builtin_amdgcn_mfma_f32_16x16x32_bf16(a, b0, acc0, 0, 0, 0);
        acc1 = __builtin_amdgcn_mfma_f32_16x16x32_bf16(a, b1, acc1, 0, 0, 0);
    }
    #pragma unroll
    for (int j = 0; j < 4; j++) {
        int rr = grow0 + kb * 4 + j;
        if (rr < nrows) {
            float d = dinv[rr];
            OUT[(size_t)rr * 32 + m]      = f2bf(acc0[j] * d);
            OUT[(size_t)rr * 32 + 16 + m] = f2bf(acc1[j] * d);
        }
    }
}

// ------------------------------------------------------------------
// bf16 gather over an edge sub-range [ea, eb): 8-lane group, lane owns
// channels [c0..c0+3], 4 independent chains (proven R10 inner loop).
__device__ __forceinline__ float4 agg_gather_half(const unsigned short* __restrict__ HS,
                                                  const int* __restrict__ col,
                                                  int ea, int eb, int c0) {
    float4 a0 = {0,0,0,0}, a1 = {0,0,0,0}, a2 = {0,0,0,0}, a3 = {0,0,0,0};
    int e = ea;
    for (; e + 3 < eb; e += 4) {
        int sA = col[e], sB = col[e + 1], sC = col[e + 2], sD = col[e + 3];
        ushort4 uA = *(const ushort4*)&HS[(size_t)sA * 32 + c0];
        ushort4 uB = *(const ushort4*)&HS[(size_t)sB * 32 + c0];
        ushort4 uC = *(const ushort4*)&HS[(size_t)sC * 32 + c0];
        ushort4 uD = *(const ushort4*)&HS[(size_t)sD * 32 + c0];
        a0.x += bf2f(uA.x); a0.y += bf2f(uA.y); a0.z += bf2f(uA.z); a0.w += bf2f(uA.w);
        a1.x += bf2f(uB.x); a1.y += bf2f(uB.y); a1.z += bf2f(uB.z); a1.w += bf2f(uB.w);
        a2.x += bf2f(uC.x); a2.y += bf2f(uC.y); a2.z += bf2f(uC.z); a2.w += bf2f(uC.w);
        a3.x += bf2f(uD.x); a3.y += bf2f(uD.y); a3.z += bf2f(uD.z); a3.w += bf2f(uD.w);
    }
    for (; e < eb; e++) {
        int sA = col[e];
        ushort4 uA = *(const ushort4*)&HS[(size_t)sA * 32 + c0];
        a0.x += bf2f(uA.x); a0.y += bf2f(uA.y); a0.z += bf2f(uA.z); a0.w += bf2f(uA.w);
    }
    float4 acc;
    acc.x = (a0.x + a1.x) + (a2.x + a3.x);
    acc.y = (a0.y + a1.y) + (a2.y + a3.y);
    acc.z = (a0.z + a1.z) + (a2.z + a3.z);
    acc.w = (a0.w + a1.w) + (a2.w + a3.w);
    return acc;
}

// full node aggregate: 16 lanes/node = 2 groups x 8 lanes; group g gathers
// its half of the edge list; cross-group shfl_xor(8) reduce; + self row.
__device__ __forceinline__ float4 agg_node16(const unsigned short* __restrict__ HS,
                                             const int* __restrict__ col,
                                             int s0, int s1, int node, int c0, int sub) {
    const int mid = s0 + ((s1 - s0) >> 1);
    const int ea = sub ? mid : s0;
    const int eb = sub ? s1 : mid;
    float4 acc = agg_gather_half(HS, col, ea, eb, c0);
    acc.x += __shfl_xor(acc.x, 8, 64);
    acc.y += __shfl_xor(acc.y, 8, 64);
    acc.z += __shfl_xor(acc.z, 8, 64);
    acc.w += __shfl_xor(acc.w, 8, 64);
    ushort4 uS = *(const ushort4*)&HS[(size_t)node * 32 + c0];
    acc.x += bf2f(uS.x); acc.y += bf2f(uS.y);
    acc.z += bf2f(uS.z); acc.w += bf2f(uS.w);
    return acc;
}

// fuse: a = relu(dinv*(agg hs1) + b1); OUT(bf16) = dinv * (a @ W2)  [32 -> 32]
__global__ __launch_bounds__(256) void k_fuse32(const unsigned short* __restrict__ HS,
                                                const int* __restrict__ row_ptr,
                                                const int* __restrict__ col,
                                                const float* __restrict__ dinv,
                                                const float* __restrict__ bin,
                                                const float* __restrict__ W,
                                                unsigned short* __restrict__ OUT, int n) {
    __shared__ float ws[32][32];
    {
        int i = threadIdx.x;                 // 256 float4s = 32x32
        int r = i / 8, c = (i % 8) * 4;
        *(float4*)&ws[r][c] = *(const float4*)&W[r * 32 + c];
    }
    __syncthreads();
    const int t    = threadIdx.x;
    const int node = blockIdx.x * 16 + t / 16;
    const int c0   = (t % 8) * 4;
    const int sub  = (t >> 3) & 1;
    if (node >= n) return;
    const int s0 = row_ptr[node], s1 = row_ptr[node + 1];
    float4 acc = agg_node16(HS, col, s0, s1, node, c0, sub);
    const float di = dinv[node];
    float4 b4 = *(const float4*)&bin[c0];
    float4 a;
    a.x = fmaxf(di * acc.x + b4.x, 0.f);
    a.y = fmaxf(di * acc.y + b4.y, 0.f);
    a.z = fmaxf(di * acc.z + b4.z, 0.f);
    a.w = fmaxf(di * acc.w + b4.w, 0.f);
    float4 o = {0,0,0,0};
    const int gb = (t & 63) & ~15;
    #pragma unroll
    for (int s = 0; s < 8; s++) {
        float4 as;
        as.x = __shfl(a.x, gb + s, 64);
        as.y = __shfl(a.y, gb + s, 64);
        as.z = __shfl(a.z, gb + s, 64);
        as.w = __shfl(a.w, gb + s, 64);
        const int k0 = s * 4;
        float4 w0 = *(const float4*)&ws[k0 + 0][c0];
        float4 w1 = *(const float4*)&ws[k0 + 1][c0];
        float4 w2 = *(const float4*)&ws[k0 + 2][c0];
        float4 w3 = *(const float4*)&ws[k0 + 3][c0];
        o.x += as.x*w0.x + as.y*w1.x + as.z*w2.x + as.w*w3.x;
        o.y += as.x*w0.y + as.y*w1.y + as.z*w2.y + as.w*w3.y;
        o.z += as.x*w0.z + as.y*w1.z + as.z*w2.z + as.w*w3.z;
        o.w += as.x*w0.w + as.y*w1.w + as.z*w2.w + as.w*w3.w;
    }
    if (sub == 0) {
        ushort4 st;
        st.x = f2bf(o.x * di); st.y = f2bf(o.y * di);
        st.z = f2bf(o.z * di); st.w = f2bf(o.w * di);
        *(ushort4*)&OUT[(size_t)node * 32 + c0] = st;
    }
}

// agg + bias + relu + dinv scale: OUT(bf16) = dinv.*relu(dinv*agg(HS)+b)
__global__ __launch_bounds__(256) void k_aggscale(const unsigned short* __restrict__ HS,
                                                  const int* __restrict__ row_ptr,
                                                  const int* __restrict__ col,
                                                  const float* __restrict__ dinv,
                                                  const float* __restrict__ bin,
                                                  unsigned short* __restrict__ OUT, int n) {
    const int t    = threadIdx.x;
    const int node = blockIdx.x * 16 + t / 16;
    const int c0   = (t % 8) * 4;
    const int sub  = (t >> 3) & 1;
    if (node >= n) return;
    const int s0 = row_ptr[node], s1 = row_ptr[node + 1];
    float4 acc = agg_node16(HS, col, s0, s1, node, c0, sub);
    if (sub == 0) {
        const float di = dinv[node];
        float4 b4 = *(const float4*)&bin[c0];
        ushort4 o;
        o.x = f2bf(di * fmaxf(di * acc.x + b4.x, 0.f));
        o.y = f2bf(di * fmaxf(di * acc.y + b4.y, 0.f));
        o.z = f2bf(di * fmaxf(di * acc.z + b4.z, 0.f));
        o.w = f2bf(di * fmaxf(di * acc.w + b4.w, 0.f));
        *(ushort4*)&OUT[(size_t)node * 32 + c0] = o;
    }
}

// final: g = dinv*(agg ys2); h3 = g @ W3 + b3 [32->64]; out = log_softmax(h3)
__global__ __launch_bounds__(256) void k_fuseC(const unsigned short* __restrict__ YS,
                                               const int* __restrict__ row_ptr,
                                               const int* __restrict__ col,
                                               const float* __restrict__ dinv,
                                               const float* __restrict__ b3,
                                               const float* __restrict__ W,
                                               float* __restrict__ OUT, int n) {
    __shared__ float ws[32][64];
    {
        int i = threadIdx.x;                  // 512 float4s = 32x64 -> 2 each
        int r0w = i / 16, cw = (i % 16) * 4;
        *(float4*)&ws[r0w][cw]      = *(const float4*)&W[r0w * 64 + cw];
        *(float4*)&ws[r0w + 16][cw] = *(const float4*)&W[(r0w + 16) * 64 + cw];
    }
    __syncthreads();
    const int t    = threadIdx.x;
    const int node = blockIdx.x * 16 + t / 16;
    const int c0   = (t % 8) * 4;
    const int sub  = (t >> 3) & 1;
    if (node >= n) return;
    const int s0 = row_ptr[node], s1 = row_ptr[node + 1];
    float4 acc = agg_node16(YS, col, s0, s1, node, c0, sub);
    const float di = dinv[node];
    float4 g;
    g.x = di * acc.x; g.y = di * acc.y; g.z = di * acc.z; g.w = di * acc.w;
    float4 oL = {0,0,0,0}, oH = {0,0,0,0};
    const int gb = (t & 63) & ~15;
    #pragma unroll
    for (int s = 0; s < 8; s++) {
        float4 gs;
        gs.x = __shfl(g.x, gb + s, 64);
        gs.y = __shfl(g.y, gb + s, 64);
        gs.z = __shfl(g.z, gb + s, 64);
        gs.w = __shfl(g.w, gb + s, 64);
        const int k0 = s * 4;
        #pragma unroll
        for (int q = 0; q < 4; q++) {
            float gv = (q == 0) ? gs.x : (q == 1) ? gs.y : (q == 2) ? gs.z : gs.w;
            float4 wL = *(const float4*)&ws[k0 + q][c0];
            float4 wH = *(const float4*)&ws[k0 + q][32 + c0];
            oL.x += gv * wL.x; oL.y += gv * wL.y; oL.z += gv * wL.z; oL.w += gv * wL.w;
            oH.x += gv * wH.x; oH.y += gv * wH.y; oH.z += gv * wH.z; oH.w += gv * wH.w;
        }
    }
    float4 bL = *(const float4*)&b3[c0];
    float4 bH = *(const float4*)&b3[32 + c0];
    oL.x += bL.x; oL.y += bL.y; oL.z += bL.z; oL.w += bL.w;
    oH.x += bH.x; oH.y += bH.y; oH.z += bH.z; oH.w += bH.w;
    float m = fmaxf(fmaxf(fmaxf(oL.x, oL.y), fmaxf(oL.z, oL.w)),
                    fmaxf(fmaxf(oH.x, oH.y), fmaxf(oH.z, oH.w)));
    #pragma unroll
    for (int off = 1; off < 8; off <<= 1) m = fmaxf(m, __shfl_xor(m, off, 64));
    float sum = expf(oL.x - m) + expf(oL.y - m) + expf(oL.z - m) + expf(oL.w - m)
              + expf(oH.x - m) + expf(oH.y - m) + expf(oH.z - m) + expf(oH.w - m);
    #pragma unroll
    for (int off = 1; off < 8; off <<= 1) sum += __shfl_xor(sum, off, 64);
    float lse = m + logf(sum);
    if (sub == 0) {
        float4 rL, rH;
        rL.x = oL.x - lse; rL.y = oL.y - lse; rL.z = oL.z - lse; rL.w = oL.w - lse;
        rH.x = oH.x - lse; rH.y = oH.y - lse; rH.z = oH.z - lse; rH.w = oH.w - lse;
        *(float4*)&OUT[(size_t)node * 64 + c0]      = rL;
        *(float4*)&OUT[(size_t)node * 64 + 32 + c0] = rH;
    }
}

// ------------------------------------------------------------------
extern "C" void kernel_launch(void* const* d_in, const int* in_sizes, int n_in,
                              void* d_out, int out_size, void* d_ws, size_t ws_size,
                              hipStream_t stream) {
    const float* x  = (const float*)d_in[0];
    const int*   ei = (const int*)d_in[1];
    const float* W1 = (const float*)d_in[2];
    const float* b1 = (const float*)d_in[3];
    const float* W2 = (const float*)d_in[4];
    const float* b2 = (const float*)d_in[5];
    const float* W3 = (const float*)d_in[6];
    const float* b3 = (const float*)d_in[7];
    float* out = (float*)d_out;

    const int E = in_sizes[1] / 2;
    const int n = NN;
    const int* src = ei;
    const int* dst = ei + E;

    char* p = (char*)d_ws;
    auto alloc = [&](size_t bytes) -> void* {
        void* r = p;
        p += (bytes + 63) & ~(size_t)63;
        return r;
    };
    int*            gcnt    = (int*)alloc((size_t)NBUCK * NBLK_A * 4);
    int*            gofs    = (int*)alloc((size_t)NBUCK * NBLK_A * 4);
    int*            bcnt    = (int*)alloc((size_t)NBUCK * 4);
    int*            bbase   = (int*)alloc((size_t)(NBUCK + 1) * 4);
    unsigned*       part    = (unsigned*)alloc((size_t)E * 4);
    int*            row_ptr = (int*)alloc((size_t)(n + 1) * 4);
    int*            col     = (int*)alloc((size_t)E * 4);
    float*          dinv    = (float*)alloc((size_t)n * 4);
    unsigned short* wtbf    = (unsigned short*)alloc((size_t)512 * 32 * 2);
    unsigned short* hs1     = (unsigned short*)alloc((size_t)n * 32 * 2);  // reused as ys2
    unsigned short* hs2     = (unsigned short*)alloc((size_t)n * 32 * 2);

    const int chunk = CDIV(E, NBLK_A);

    k_count<<<NBLK_A + 2, 256, 0, stream>>>(dst, W1, gcnt, wtbf, E, chunk);
    k_scan2<<<NBUCK, 256, 0, stream>>>(gcnt, gofs, bcnt);
    k_scanB<<<1, 512, 0, stream>>>(bcnt, bbase, E);
    k_bpart<<<NBLK_A, 256, 0, stream>>>(src, dst, bbase, gofs, part, E, chunk);
    k_bbuild<<<NBUCK, 256, 0, stream>>>(part, bbase, row_ptr, dinv, col, n, E);

    // L1 GEMM (MFMA bf16): hs1 = bf16(dinv.*(x @ W1))
    k_gemm1<<<CDIV(n, 64), 256, 0, stream>>>(x, wtbf, dinv, hs1, n);
    // L1 agg + relu + L2 GEMM: hs2 = bf16(dinv.*(relu(dinv*agg(hs1)+b1) @ W2))
    k_fuse32<<<CDIV(n, 16), 256, 0, stream>>>(hs1, row_ptr, col, dinv, b1, W2, hs2, n);
    // L2 agg + relu + scale: ys2 = bf16(dinv.*relu(dinv*agg(hs2)+b2))  (reuse hs1)
    k_aggscale<<<CDIV(n, 16), 256, 0, stream>>>(hs2, row_ptr, col, dinv, b2, hs1, n);
    // L3 (commuted): out = lsm( (dinv*agg(ys2)) @ W3 + b3 )
    k_fuseC<<<CDIV(n, 16), 256, 0, stream>>>(hs1, row_ptr, col, dinv, b3, W3, out, n);
}

// Round 15
// 175.249 us; speedup vs baseline: 1.1743x; 1.1743x over previous
//
#include <hip/hip_runtime.h>
#include <math.h>

static constexpr int NN    = 100000;
static constexpr int NBUCK = (NN + 255) / 256;   // 391 buckets of 256 nodes
static constexpr int NBLK_A = 256;               // edge-pass blocks

#define CDIV(a,b) (((a)+(b)-1)/(b))

typedef __attribute__((ext_vector_type(8))) short bf16x8;
typedef __attribute__((ext_vector_type(4))) float f32x4;

// bf16 helpers (round-to-nearest-even store, shift load)
__device__ __forceinline__ float bf2f(unsigned short u) {
    return __uint_as_float(((unsigned)u) << 16);
}
__device__ __forceinline__ unsigned short f2bf(float f) {
    unsigned u = __float_as_uint(f);
    u += 0x7fffu + ((u >> 16) & 1u);
    return (unsigned short)(u >> 16);
}

// ------------------------------------------------------------------
// A1: blocks 0..255: per-block bucket counts -> gcnt[bucket][block].
// Blocks 256,257: convert W1 to swizzled bf16 image.
__global__ __launch_bounds__(256) void k_count(const int* __restrict__ dst,
                                               const float* __restrict__ W1,
                                               int* __restrict__ gcnt,
                                               unsigned short* __restrict__ WT,
                                               int E, int chunk) {
    const int b = blockIdx.x;
    const int t = threadIdx.x;
    if (b >= NBLK_A) {
        int base = (b - NBLK_A) * 8192 + t;   // 2 blocks x 8192
        #pragma unroll
        for (int i = 0; i < 32; i++) {
            int idx = base + i * 256;
            int k = idx >> 5, c = idx & 31;
            WT[c * 512 + (((k >> 3) ^ (c & 7)) << 3) + (k & 7)] = f2bf(W1[idx]);
        }
        return;
    }
    __shared__ int lc[NBUCK];
    for (int i = t; i < NBUCK; i += 256) lc[i] = 0;
    __syncthreads();
    int e0 = b * chunk;
    int e1 = e0 + chunk; if (e1 > E) e1 = E;
    for (int e = e0 + t; e < e1; e += 256)
        atomicAdd(&lc[dst[e] >> 8], 1);
    __syncthreads();
    for (int i = t; i < NBUCK; i += 256)
        gcnt[i * NBLK_A + b] = lc[i];
}

// A2: per-bucket exclusive scan over the 256 block-counts -> gofs, totals
__global__ __launch_bounds__(256) void k_scan2(const int* __restrict__ gcnt,
                                               int* __restrict__ gofs,
                                               int* __restrict__ bcnt) {
    const int b = blockIdx.x, t = threadIdx.x;
    __shared__ int sm[256];
    int v = gcnt[b * NBLK_A + t];
    sm[t] = v; __syncthreads();
    for (int off = 1; off < 256; off <<= 1) {
        int u = (t >= off) ? sm[t - off] : 0;
        __syncthreads();
        sm[t] += u;
        __syncthreads();
    }
    gofs[b * NBLK_A + t] = sm[t] - v;
    if (t == 255) bcnt[b] = sm[255];
}

// A3: exclusive scan of bucket totals -> bbase
__global__ __launch_bounds__(512) void k_scanB(const int* __restrict__ bcnt,
                                               int* __restrict__ bbase, int E) {
    __shared__ int sm[512];
    int t = threadIdx.x;
    int v = (t < NBUCK) ? bcnt[t] : 0;
    sm[t] = v; __syncthreads();
    for (int off = 1; off < 512; off <<= 1) {
        int u = (t >= off) ? sm[t - off] : 0;
        __syncthreads();
        sm[t] += u;
        __syncthreads();
    }
    if (t < NBUCK) bbase[t] = sm[t] - v;
    if (t == 0) bbase[NBUCK] = E;
}

// A4: single-pass partition: run starts known per (bucket, block)
__global__ __launch_bounds__(256) void k_bpart(const int* __restrict__ src,
                                               const int* __restrict__ dst,
                                               const int* __restrict__ bbase,
                                               const int* __restrict__ gofs,
                                               unsigned int* __restrict__ part,
                                               int E, int chunk) {
    __shared__ int boff[NBUCK];
    __shared__ int lc[NBUCK];
    const int blk = blockIdx.x;
    for (int i = threadIdx.x; i < NBUCK; i += 256) {
        boff[i] = bbase[i] + gofs[i * NBLK_A + blk];
        lc[i] = 0;
    }
    __syncthreads();
    int e0 = blk * chunk;
    int e1 = e0 + chunk; if (e1 > E) e1 = E;
    for (int e = e0 + threadIdx.x; e < e1; e += 256) {
        int d = dst[e];
        int b = d >> 8;
        int pos = boff[b] + atomicAdd(&lc[b], 1);
        part[pos] = ((unsigned)src[e] << 8) | (unsigned)(d & 255);
    }
}

// B: per-bucket CSR finalize: row_ptr, dinv, col (all writes bucket-local)
__global__ __launch_bounds__(256) void k_bbuild(const unsigned int* __restrict__ part,
                                                const int* __restrict__ bbase,
                                                int* __restrict__ row_ptr,
                                                float* __restrict__ dinv,
                                                int* __restrict__ col, int n, int E) {
    __shared__ int hist[256];
    __shared__ int excl[256];
    __shared__ int fill[256];
    const int b = blockIdx.x;
    const int t = threadIdx.x;
    const int e0 = bbase[b], e1 = bbase[b + 1];
    hist[t] = 0; fill[t] = 0;
    __syncthreads();
    for (int e = e0 + t; e < e1; e += 256)
        atomicAdd(&hist[part[e] & 255], 1);
    __syncthreads();
    int v = hist[t];
    excl[t] = v; __syncthreads();
    for (int off = 1; off < 256; off <<= 1) {
        int u = (t >= off) ? excl[t - off] : 0;
        __syncthreads();
        excl[t] += u;
        __syncthreads();
    }
    int ex = excl[t] - v;
    int g = b * 256 + t;
    if (g < n) {
        row_ptr[g] = e0 + ex;
        dinv[g] = rsqrtf((float)(v + 1));
    }
    if (b == 0 && t == 0) row_ptr[n] = E;
    excl[t] = e0 + ex;
    __syncthreads();
    for (int e = e0 + t; e < e1; e += 256) {
        unsigned u = part[e];
        int ld = u & 255;
        int pos = excl[ld] + atomicAdd(&fill[ld], 1);
        col[pos] = (int)(u >> 8);
    }
}

// ------------------------------------------------------------------
// Layer-1 GEMM via MFMA bf16 (proven R10 structure).
__global__ __launch_bounds__(256) void k_gemm1(const float* __restrict__ X,
                                               const unsigned short* __restrict__ WT,
                                               const float* __restrict__ dinv,
                                               unsigned short* __restrict__ OUT,
                                               int nrows) {
    __shared__ unsigned short wt[32][512];   // 32 KB
    const int t = threadIdx.x;
    {
        const uint4* s = (const uint4*)WT;
        uint4* d = (uint4*)&wt[0][0];
        #pragma unroll
        for (int i = 0; i < 8; i++) d[t + 256 * i] = s[t + 256 * i];
    }
    __syncthreads();

    const int lane  = t & 63;
    const int w     = t >> 6;
    const int grow0 = blockIdx.x * 64 + w * 16;
    const int m     = lane & 15;
    const int kb    = lane >> 4;             // 0..3
    int row = grow0 + m; if (row > nrows - 1) row = nrows - 1;
    const float* xrow = X + (size_t)row * 512 + kb * 8;

    f32x4 acc0 = {0.f, 0.f, 0.f, 0.f};
    f32x4 acc1 = {0.f, 0.f, 0.f, 0.f};
    const int mx  = m & 7;
    const unsigned short* wrow0 = &wt[m][0];
    const unsigned short* wrow1 = &wt[m + 16][0];

    #pragma unroll 4
    for (int kk = 0; kk < 512; kk += 32) {
        float4 xa = *(const float4*)(xrow + kk);
        float4 xb = *(const float4*)(xrow + kk + 4);
        bf16x8 a;
        a[0] = (short)f2bf(xa.x); a[1] = (short)f2bf(xa.y);
        a[2] = (short)f2bf(xa.z); a[3] = (short)f2bf(xa.w);
        a[4] = (short)f2bf(xb.x); a[5] = (short)f2bf(xb.y);
        a[6] = (short)f2bf(xb.z); a[7] = (short)f2bf(xb.w);
        const int g = (kk >> 3) + kb;        // 0..63
        bf16x8 b0 = *(const bf16x8*)&wrow0[((g ^ mx) & 63) * 8];
        bf16x8 b1 = *(const bf16x8*)&wrow1[((g ^ mx) & 63) * 8];
        acc0 = __builtin_amdgcn_mfma_f32_16x16x32_bf16(a, b0, acc0, 0, 0, 0);
        acc1 = __builtin_amdgcn_mfma_f32_16x16x32_bf16(a, b1, acc1, 0, 0, 0);
    }
    #pragma unroll
    for (int j = 0; j < 4; j++) {
        int rr = grow0 + kb * 4 + j;
        if (rr < nrows) {
            float d = dinv[rr];
            OUT[(size_t)rr * 32 + m]      = f2bf(acc0[j] * d);
            OUT[(size_t)rr * 32 + 16 + m] = f2bf(acc1[j] * d);
        }
    }
}

// ------------------------------------------------------------------
// bf16 gather-aggregate core: 8 lanes/node, lane owns channels [c0..c0+3],
// 4 independent chains (proven R10 structure).
__device__ __forceinline__ float4 agg_gather_bf16(const unsigned short* __restrict__ HS,
                                                  const int* __restrict__ col,
                                                  int s0, int s1, int node, int c0) {
    float4 a0 = {0,0,0,0}, a1 = {0,0,0,0}, a2 = {0,0,0,0}, a3 = {0,0,0,0};
    int e = s0;
    for (; e + 3 < s1; e += 4) {
        int sA = col[e], sB = col[e + 1], sC = col[e + 2], sD = col[e + 3];
        ushort4 uA = *(const ushort4*)&HS[(size_t)sA * 32 + c0];
        ushort4 uB = *(const ushort4*)&HS[(size_t)sB * 32 + c0];
        ushort4 uC = *(const ushort4*)&HS[(size_t)sC * 32 + c0];
        ushort4 uD = *(const ushort4*)&HS[(size_t)sD * 32 + c0];
        a0.x += bf2f(uA.x); a0.y += bf2f(uA.y); a0.z += bf2f(uA.z); a0.w += bf2f(uA.w);
        a1.x += bf2f(uB.x); a1.y += bf2f(uB.y); a1.z += bf2f(uB.z); a1.w += bf2f(uB.w);
        a2.x += bf2f(uC.x); a2.y += bf2f(uC.y); a2.z += bf2f(uC.z); a2.w += bf2f(uC.w);
        a3.x += bf2f(uD.x); a3.y += bf2f(uD.y); a3.z += bf2f(uD.z); a3.w += bf2f(uD.w);
    }
    for (; e < s1; e++) {
        int sA = col[e];
        ushort4 uA = *(const ushort4*)&HS[(size_t)sA * 32 + c0];
        a0.x += bf2f(uA.x); a0.y += bf2f(uA.y); a0.z += bf2f(uA.z); a0.w += bf2f(uA.w);
    }
    ushort4 uS = *(const ushort4*)&HS[(size_t)node * 32 + c0];
    float4 acc;
    acc.x = a0.x + a1.x + a2.x + a3.x + bf2f(uS.x);
    acc.y = a0.y + a1.y + a2.y + a3.y + bf2f(uS.y);
    acc.z = a0.z + a1.z + a2.z + a3.z + bf2f(uS.z);
    acc.w = a0.w + a1.w + a2.w + a3.w + bf2f(uS.w);
    return acc;
}

// fuse: a = relu(dinv*(agg hs1) + b1); OUT(bf16) = dinv * (a @ W2)  [32 -> 32]
__global__ __launch_bounds__(256) void k_fuse32(const unsigned short* __restrict__ HS,
                                                const int* __restrict__ row_ptr,
                                                const int* __restrict__ col,
                                                const float* __restrict__ dinv,
                                                const float* __restrict__ bin,
                                                const float* __restrict__ W,
                                                unsigned short* __restrict__ OUT, int n) {
    __shared__ float ws[32][32];
    {
        int i = threadIdx.x;                 // 256 float4s = 32x32
        int r = i / 8, c = (i % 8) * 4;
        *(float4*)&ws[r][c] = *(const float4*)&W[r * 32 + c];
    }
    __syncthreads();
    const int t    = threadIdx.x;
    const int node = blockIdx.x * 32 + t / 8;
    const int c0   = (t % 8) * 4;
    if (node >= n) return;
    const int s0 = row_ptr[node], s1 = row_ptr[node + 1];
    float4 acc = agg_gather_bf16(HS, col, s0, s1, node, c0);
    const float di = dinv[node];
    float4 b4 = *(const float4*)&bin[c0];
    float4 a;
    a.x = fmaxf(di * acc.x + b4.x, 0.f);
    a.y = fmaxf(di * acc.y + b4.y, 0.f);
    a.z = fmaxf(di * acc.z + b4.z, 0.f);
    a.w = fmaxf(di * acc.w + b4.w, 0.f);
    float4 o = {0,0,0,0};
    const int gb = (t & 63) & ~7;
    #pragma unroll
    for (int s = 0; s < 8; s++) {
        float4 as;
        as.x = __shfl(a.x, gb + s, 64);
        as.y = __shfl(a.y, gb + s, 64);
        as.z = __shfl(a.z, gb + s, 64);
        as.w = __shfl(a.w, gb + s, 64);
        const int k0 = s * 4;
        float4 w0 = *(const float4*)&ws[k0 + 0][c0];
        float4 w1 = *(const float4*)&ws[k0 + 1][c0];
        float4 w2 = *(const float4*)&ws[k0 + 2][c0];
        float4 w3 = *(const float4*)&ws[k0 + 3][c0];
        o.x += as.x*w0.x + as.y*w1.x + as.z*w2.x + as.w*w3.x;
        o.y += as.x*w0.y + as.y*w1.y + as.z*w2.y + as.w*w3.y;
        o.z += as.x*w0.z + as.y*w1.z + as.z*w2.z + as.w*w3.z;
        o.w += as.x*w0.w + as.y*w1.w + as.z*w2.w + as.w*w3.w;
    }
    ushort4 st;
    st.x = f2bf(o.x * di); st.y = f2bf(o.y * di);
    st.z = f2bf(o.z * di); st.w = f2bf(o.w * di);
    *(ushort4*)&OUT[(size_t)node * 32 + c0] = st;
}

// agg + bias + relu + dinv scale: OUT(bf16) = dinv.*relu(dinv*agg(HS)+b)
__global__ __launch_bounds__(256) void k_aggscale(const unsigned short* __restrict__ HS,
                                                  const int* __restrict__ row_ptr,
                                                  const int* __restrict__ col,
                                                  const float* __restrict__ dinv,
                                                  const float* __restrict__ bin,
                                                  unsigned short* __restrict__ OUT, int n) {
    const int t    = threadIdx.x;
    const int node = blockIdx.x * 32 + t / 8;
    const int c0   = (t % 8) * 4;
    if (node >= n) return;
    const int s0 = row_ptr[node], s1 = row_ptr[node + 1];
    float4 acc = agg_gather_bf16(HS, col, s0, s1, node, c0);
    const float di = dinv[node];
    float4 b4 = *(const float4*)&bin[c0];
    ushort4 o;
    o.x = f2bf(di * fmaxf(di * acc.x + b4.x, 0.f));
    o.y = f2bf(di * fmaxf(di * acc.y + b4.y, 0.f));
    o.z = f2bf(di * fmaxf(di * acc.z + b4.z, 0.f));
    o.w = f2bf(di * fmaxf(di * acc.w + b4.w, 0.f));
    *(ushort4*)&OUT[(size_t)node * 32 + c0] = o;
}

// final: g = dinv*(agg ys2); h3 = g @ W3 + b3 [32->64]; out = log_softmax(h3)
__global__ __launch_bounds__(256) void k_fuseC(const unsigned short* __restrict__ YS,
                                               const int* __restrict__ row_ptr,
                                               const int* __restrict__ col,
                                               const float* __restrict__ dinv,
                                               const float* __restrict__ b3,
                                               const float* __restrict__ W,
                                               float* __restrict__ OUT, int n) {
    __shared__ float ws[32][64];
    {
        int i = threadIdx.x;                  // 512 float4s = 32x64 -> 2 each
        int r0w = i / 16, cw = (i % 16) * 4;
        *(float4*)&ws[r0w][cw]      = *(const float4*)&W[r0w * 64 + cw];
        *(float4*)&ws[r0w + 16][cw] = *(const float4*)&W[(r0w + 16) * 64 + cw];
    }
    __syncthreads();
    const int t    = threadIdx.x;
    const int node = blockIdx.x * 32 + t / 8;
    const int c0   = (t % 8) * 4;
    if (node >= n) return;
    const int s0 = row_ptr[node], s1 = row_ptr[node + 1];
    float4 acc = agg_gather_bf16(YS, col, s0, s1, node, c0);
    const float di = dinv[node];
    float4 g;
    g.x = di * acc.x; g.y = di * acc.y; g.z = di * acc.z; g.w = di * acc.w;
    float4 oL = {0,0,0,0}, oH = {0,0,0,0};
    const int gb = (t & 63) & ~7;
    #pragma unroll
    for (int s = 0; s < 8; s++) {
        float4 gs;
        gs.x = __shfl(g.x, gb + s, 64);
        gs.y = __shfl(g.y, gb + s, 64);
        gs.z = __shfl(g.z, gb + s, 64);
        gs.w = __shfl(g.w, gb + s, 64);
        const int k0 = s * 4;
        #pragma unroll
        for (int q = 0; q < 4; q++) {
            float gv = (q == 0) ? gs.x : (q == 1) ? gs.y : (q == 2) ? gs.z : gs.w;
            float4 wL = *(const float4*)&ws[k0 + q][c0];
            float4 wH = *(const float4*)&ws[k0 + q][32 + c0];
            oL.x += gv * wL.x; oL.y += gv * wL.y; oL.z += gv * wL.z; oL.w += gv * wL.w;
            oH.x += gv * wH.x; oH.y += gv * wH.y; oH.z += gv * wH.z; oH.w += gv * wH.w;
        }
    }
    float4 bL = *(const float4*)&b3[c0];
    float4 bH = *(const float4*)&b3[32 + c0];
    oL.x += bL.x; oL.y += bL.y; oL.z += bL.z; oL.w += bL.w;
    oH.x += bH.x; oH.y += bH.y; oH.z += bH.z; oH.w += bH.w;
    float m = fmaxf(fmaxf(fmaxf(oL.x, oL.y), fmaxf(oL.z, oL.w)),
                    fmaxf(fmaxf(oH.x, oH.y), fmaxf(oH.z, oH.w)));
    #pragma unroll
    for (int off = 1; off < 8; off <<= 1) m = fmaxf(m, __shfl_xor(m, off, 64));
    float sum = expf(oL.x - m) + expf(oL.y - m) + expf(oL.z - m) + expf(oL.w - m)
              + expf(oH.x - m) + expf(oH.y - m) + expf(oH.z - m) + expf(oH.w - m);
    #pragma unroll
    for (int off = 1; off < 8; off <<= 1) sum += __shfl_xor(sum, off, 64);
    float lse = m + logf(sum);
    float4 rL, rH;
    rL.x = oL.x - lse; rL.y = oL.y - lse; rL.z = oL.z - lse; rL.w = oL.w - lse;
    rH.x = oH.x - lse; rH.y = oH.y - lse; rH.z = oH.z - lse; rH.w = oH.w - lse;
    *(float4*)&OUT[(size_t)node * 64 + c0]      = rL;
    *(float4*)&OUT[(size_t)node * 64 + 32 + c0] = rH;
}

// ------------------------------------------------------------------
extern "C" void kernel_launch(void* const* d_in, const int* in_sizes, int n_in,
                              void* d_out, int out_size, void* d_ws, size_t ws_size,
                              hipStream_t stream) {
    const float* x  = (const float*)d_in[0];
    const int*   ei = (const int*)d_in[1];
    const float* W1 = (const float*)d_in[2];
    const float* b1 = (const float*)d_in[3];
    const float* W2 = (const float*)d_in[4];
    const float* b2 = (const float*)d_in[5];
    const float* W3 = (const float*)d_in[6];
    const float* b3 = (const float*)d_in[7];
    float* out = (float*)d_out;

    const int E = in_sizes[1] / 2;
    const int n = NN;
    const int* src = ei;
    const int* dst = ei + E;

    char* p = (char*)d_ws;
    auto alloc = [&](size_t bytes) -> void* {
        void* r = p;
        p += (bytes + 63) & ~(size_t)63;
        return r;
    };
    int*            gcnt    = (int*)alloc((size_t)NBUCK * NBLK_A * 4);
    int*            gofs    = (int*)alloc((size_t)NBUCK * NBLK_A * 4);
    int*            bcnt    = (int*)alloc((size_t)NBUCK * 4);
    int*            bbase   = (int*)alloc((size_t)(NBUCK + 1) * 4);
    unsigned*       part    = (unsigned*)alloc((size_t)E * 4);
    int*            row_ptr = (int*)alloc((size_t)(n + 1) * 4);
    int*            col     = (int*)alloc((size_t)E * 4);
    float*          dinv    = (float*)alloc((size_t)n * 4);
    unsigned short* wtbf    = (unsigned short*)alloc((size_t)512 * 32 * 2);
    unsigned short* hs1     = (unsigned short*)alloc((size_t)n * 32 * 2);  // reused as ys2
    unsigned short* hs2     = (unsigned short*)alloc((size_t)n * 32 * 2);

    const int chunk = CDIV(E, NBLK_A);

    k_count<<<NBLK_A + 2, 256, 0, stream>>>(dst, W1, gcnt, wtbf, E, chunk);
    k_scan2<<<NBUCK, 256, 0, stream>>>(gcnt, gofs, bcnt);
    k_scanB<<<1, 512, 0, stream>>>(bcnt, bbase, E);
    k_bpart<<<NBLK_A, 256, 0, stream>>>(src, dst, bbase, gofs, part, E, chunk);
    k_bbuild<<<NBUCK, 256, 0, stream>>>(part, bbase, row_ptr, dinv, col, n, E);

    // L1 GEMM (MFMA bf16): hs1 = bf16(dinv.*(x @ W1))
    k_gemm1<<<CDIV(n, 64), 256, 0, stream>>>(x, wtbf, dinv, hs1, n);
    // L1 agg + relu + L2 GEMM: hs2 = bf16(dinv.*(relu(dinv*agg(hs1)+b1) @ W2))
    k_fuse32<<<CDIV(n, 32), 256, 0, stream>>>(hs1, row_ptr, col, dinv, b1, W2, hs2, n);
    // L2 agg + relu + scale: ys2 = bf16(dinv.*relu(dinv*agg(hs2)+b2))  (reuse hs1)
    k_aggscale<<<CDIV(n, 32), 256, 0, stream>>>(hs2, row_ptr, col, dinv, b2, hs1, n);
    // L3 (commuted): out = lsm( (dinv*agg(ys2)) @ W3 + b3 )
    k_fuseC<<<CDIV(n, 32), 256, 0, stream>>>(hs1, row_ptr, col, dinv, b3, W3, out, n);
}